// Round 5
// baseline (243.913 us; speedup 1.0000x reference)
//
#include <hip/hip_runtime.h>
#include <hip/hip_bf16.h>
#include <cstdint>

using u16 = unsigned short;
using u32 = unsigned int;

typedef __bf16 bf16x8 __attribute__((ext_vector_type(8)));
typedef float  f32x4  __attribute__((ext_vector_type(4)));

__device__ __forceinline__ u16 f2b(float f) {
    u32 u = __builtin_bit_cast(u32, f);
    u += 0x7fffu + ((u >> 16) & 1u);
    return (u16)(u >> 16);
}

// async global->LDS, 16B per lane; lds dst is wave-uniform base + lane*16
__device__ __forceinline__ void gload_lds16(const u16* g, u16* l) {
    __builtin_amdgcn_global_load_lds(
        (const __attribute__((address_space(1))) void*)g,
        (__attribute__((address_space(3))) void*)l,
        16, 0, 0);
}

// ---------------------------------------------------------------------------
// pack: fp32 -> bf16 casts (x, Wq|Wk|Wv concat, Wo) + bias concat bq|bk|bv
// ---------------------------------------------------------------------------
__launch_bounds__(256)
__global__ void pack_kernel(const float* __restrict__ x,
                            const float* __restrict__ Wq,
                            const float* __restrict__ Wk,
                            const float* __restrict__ Wv,
                            const float* __restrict__ Wo,
                            const float* __restrict__ bq,
                            const float* __restrict__ bk,
                            const float* __restrict__ bv,
                            u16* __restrict__ xb,
                            u16* __restrict__ Wqkvb,
                            u16* __restrict__ Wob,
                            float* __restrict__ bqkv)
{
    int c = blockIdx.x * 256 + threadIdx.x;   // 0 .. 1081343
    long e = (long)c * 8;
    const float* src; u16* dst; long off;
    if (e < 6291456L)      { src = x;  dst = xb;              off = e; }
    else if (e < 6881280L) { src = Wq; dst = Wqkvb;           off = e - 6291456L; }
    else if (e < 7471104L) { src = Wk; dst = Wqkvb + 589824;  off = e - 6881280L; }
    else if (e < 8060928L) { src = Wv; dst = Wqkvb + 1179648; off = e - 7471104L; }
    else                   { src = Wo; dst = Wob;             off = e - 8060928L; }
    float4 v0 = *(const float4*)(src + off);
    float4 v1 = *(const float4*)(src + off + 4);
    union { u16 u[8]; uint4 q; } o;
    o.u[0] = f2b(v0.x); o.u[1] = f2b(v0.y); o.u[2] = f2b(v0.z); o.u[3] = f2b(v0.w);
    o.u[4] = f2b(v1.x); o.u[5] = f2b(v1.y); o.u[6] = f2b(v1.z); o.u[7] = f2b(v1.w);
    *(uint4*)(dst + off) = o.q;
    if (c < 768)        bqkv[c] = bq[c];
    else if (c < 1536)  bqkv[c] = bk[c - 768];
    else if (c < 2304)  bqkv[c] = bv[c - 1536];
}

// ---------------------------------------------------------------------------
// gemm_bt: C[m,n] = sum_k A[m,k] * B[n,k] (bf16, K-contiguous), 128x128 tile,
// 4 waves, dbuf LDS, global_load_lds staging.
// MODE 0: QKV epilogue (q|k + bias -> C; v cols transposed -> vTout)
// MODE 4: out = xres + beta*(acc + bias[col]) f32
// ---------------------------------------------------------------------------
template<int MODE>
__launch_bounds__(256)
__global__ void gemm_bt(const u16* __restrict__ A, int lda, long sAz,
                        const u16* __restrict__ B, int ldb, long sBz,
                        void* __restrict__ Cv, int ldc, long sCz,
                        int K,
                        const float* __restrict__ bias,
                        const float* __restrict__ xres,
                        const float* __restrict__ betaPtr,
                        float scale,
                        u16* __restrict__ vTout)
{
    __shared__ u16 As[2][128 * 32];
    __shared__ u16 Bs[2][128 * 32];

    const int tid  = threadIdx.x;
    const int g    = blockIdx.z;
    const u16* Ab = A + (long)g * sAz + (long)blockIdx.y * 128 * lda;
    const u16* Bb = B + (long)g * sBz + (long)blockIdx.x * 128 * ldb;

    const int wave = tid >> 6, lane = tid & 63;
    const int wm = (wave >> 1) * 64, wn = (wave & 1) * 64;
    const int ln15 = lane & 15, lq = lane >> 4;

    f32x4 acc[4][4];
#pragma unroll
    for (int i = 0; i < 4; i++)
#pragma unroll
        for (int j = 0; j < 4; j++)
            acc[i][j] = (f32x4){0.f, 0.f, 0.f, 0.f};

    const int c0 = wave * 2, c1 = wave * 2 + 1;
    const int sr0 = c0 * 16 + (lane >> 2), sc = (lane & 3) * 8;
    const int sr1 = c1 * 16 + (lane >> 2);
    const u16* Ag0 = Ab + (long)sr0 * lda + sc;
    const u16* Ag1 = Ab + (long)sr1 * lda + sc;
    const u16* Bg0 = Bb + (long)sr0 * ldb + sc;
    const u16* Bg1 = Bb + (long)sr1 * ldb + sc;

    const int nk = K >> 5;

    gload_lds16(Ag0, &As[0][c0 * 512]);
    gload_lds16(Ag1, &As[0][c1 * 512]);
    gload_lds16(Bg0, &Bs[0][c0 * 512]);
    gload_lds16(Bg1, &Bs[0][c1 * 512]);

    for (int kt = 0; kt < nk; kt++) {
        const int cur = kt & 1;
        __syncthreads();
        if (kt + 1 < nk) {
            const int k0 = (kt + 1) * 32, nxt = cur ^ 1;
            gload_lds16(Ag0 + k0, &As[nxt][c0 * 512]);
            gload_lds16(Ag1 + k0, &As[nxt][c1 * 512]);
            gload_lds16(Bg0 + k0, &Bs[nxt][c0 * 512]);
            gload_lds16(Bg1 + k0, &Bs[nxt][c1 * 512]);
        }

        bf16x8 af[4], bfr[4];
#pragma unroll
        for (int i = 0; i < 4; i++)
            af[i] = *(const bf16x8*)&As[cur][(wm + i * 16 + ln15) * 32 + lq * 8];
#pragma unroll
        for (int j = 0; j < 4; j++)
            bfr[j] = *(const bf16x8*)&Bs[cur][(wn + j * 16 + ln15) * 32 + lq * 8];
#pragma unroll
        for (int i = 0; i < 4; i++)
#pragma unroll
            for (int j = 0; j < 4; j++)
                acc[i][j] = __builtin_amdgcn_mfma_f32_16x16x32_bf16(af[i], bfr[j], acc[i][j], 0, 0, 0);
    }

    const int baseRow = blockIdx.y * 128 + wm;
    const int baseCol = blockIdx.x * 128 + wn;

    if constexpr (MODE == 0) {
        if (baseCol < 1536) {
            u16* C = (u16*)Cv;
#pragma unroll
            for (int i = 0; i < 4; i++)
#pragma unroll
                for (int j = 0; j < 4; j++)
#pragma unroll
                    for (int r = 0; r < 4; r++) {
                        int row = baseRow + i * 16 + lq * 4 + r;
                        int col = baseCol + j * 16 + ln15;
                        C[(long)row * ldc + col] = f2b(acc[i][j][r] + bias[col]);
                    }
        } else {
#pragma unroll
            for (int i = 0; i < 4; i++)
#pragma unroll
                for (int j = 0; j < 4; j++) {
                    int col = baseCol + j * 16 + ln15;
                    float bb = bias[col];
                    ushort4 o;
                    o.x = f2b(acc[i][j][0] + bb);
                    o.y = f2b(acc[i][j][1] + bb);
                    o.z = f2b(acc[i][j][2] + bb);
                    o.w = f2b(acc[i][j][3] + bb);
                    *(ushort4*)(vTout + (long)(col - 1536) * 8192
                                + baseRow + i * 16 + lq * 4) = o;
                }
        }
    } else { // MODE 4
        float* C = (float*)Cv;
        float bet = betaPtr[0];
#pragma unroll
        for (int i = 0; i < 4; i++)
#pragma unroll
            for (int j = 0; j < 4; j++)
#pragma unroll
                for (int r = 0; r < 4; r++) {
                    int row = baseRow + i * 16 + lq * 4 + r;
                    int col = baseCol + j * 16 + ln15;
                    float v = xres[(long)row * ldc + col] + bet * (acc[i][j][r] + bias[col]);
                    C[(long)row * ldc + col] = v;
                }
    }
}

// ---------------------------------------------------------------------------
// attn_fused v2 — barrier-free MFMA loops.
// Block = (group g, 32-row Q tile); g = blockIdx&15 so all 16 blocks of a
// group land on one XCD (round-robin %8) -> K/V stay in that XCD's L2.
// S-phase: K/Q frags loaded global->reg (no LDS), register double-buffer.
// softmax: cross-wave via small LDS (3 barriers total in kernel).
// PV-phase: computed transposed, O^T = V^T * P^T: A-frags = vT direct
// global->reg (k=group-row contiguous), B-frags = P from swizzled 32KB LDS.
// No __syncthreads in either MFMA loop.
// P swizzle: element (row,col) at row*512 + ((col>>3 ^ (row&7))<<3) + (col&7).
// ---------------------------------------------------------------------------
__launch_bounds__(256, 1)
__global__ void attn_fused(const u16* __restrict__ qk,   // [8192,1536]
                           const u16* __restrict__ vT,   // [768,8192]
                           u16* __restrict__ dyn,        // [8192,768]
                           float scale)
{
    __shared__ u16 Pl[32 * 512];     // 32 KB
    __shared__ float smax_s[128];
    __shared__ float ssum_s[128];
    float* rinv = smax_s;            // reused after ssum barrier

    const int g   = blockIdx.x & 15;   // XCD swizzle
    const int mt  = blockIdx.x >> 4;
    const int tid = threadIdx.x;
    const int wave = tid >> 6, lane = tid & 63;
    const int ln15 = lane & 15, lq = lane >> 4;
    const long grow0 = (long)g * 512;

    // ---------------- Phase 1: S = Q K^T (no LDS, no barriers) -------------
    f32x4 accS[2][8];
#pragma unroll
    for (int i = 0; i < 2; i++)
#pragma unroll
        for (int j = 0; j < 8; j++)
            accS[i][j] = (f32x4){0.f, 0.f, 0.f, 0.f};

    // B-frag base: row = group K-row (wave*128 + j*16 + ln15), k = lq*8
    const u16* Kg = qk + (grow0 + wave * 128 + ln15) * 1536 + 768 + lq * 8;
    // A-frag base: row = Q-row (mt*32 [+16] + ln15), k = lq*8
    const u16* Qg = qk + (grow0 + mt * 32 + ln15) * 1536 + lq * 8;

    bf16x8 kb[2][8], qa[2][2];
#pragma unroll
    for (int j = 0; j < 8; j++)
        kb[0][j] = *(const bf16x8*)(Kg + j * 24576);
    qa[0][0] = *(const bf16x8*)(Qg);
    qa[0][1] = *(const bf16x8*)(Qg + 24576);

    for (int kt = 0; kt < 24; kt++) {
        const int cur = kt & 1, nxt = cur ^ 1;
        if (kt < 23) {
            const int o = (kt + 1) * 32;
#pragma unroll
            for (int j = 0; j < 8; j++)
                kb[nxt][j] = *(const bf16x8*)(Kg + j * 24576 + o);
            qa[nxt][0] = *(const bf16x8*)(Qg + o);
            qa[nxt][1] = *(const bf16x8*)(Qg + 24576 + o);
        }
#pragma unroll
        for (int j = 0; j < 8; j++) {
            accS[0][j] = __builtin_amdgcn_mfma_f32_16x16x32_bf16(qa[cur][0], kb[cur][j], accS[0][j], 0, 0, 0);
            accS[1][j] = __builtin_amdgcn_mfma_f32_16x16x32_bf16(qa[cur][1], kb[cur][j], accS[1][j], 0, 0, 0);
        }
    }

    // ---------------- Phase 2: softmax (3 barriers) -------------------------
    float mr[8];
#pragma unroll
    for (int i = 0; i < 2; i++)
#pragma unroll
        for (int r = 0; r < 4; r++) {
            float m = -3.0e38f;
#pragma unroll
            for (int j = 0; j < 8; j++) {
                accS[i][j][r] *= scale;
                m = fmaxf(m, accS[i][j][r]);
            }
            mr[i * 4 + r] = m;
        }
#pragma unroll
    for (int d = 1; d < 16; d <<= 1)
#pragma unroll
        for (int k = 0; k < 8; k++)
            mr[k] = fmaxf(mr[k], __shfl_xor(mr[k], d));
    if (ln15 == 0) {
#pragma unroll
        for (int i = 0; i < 2; i++)
#pragma unroll
            for (int r = 0; r < 4; r++)
                smax_s[(i * 16 + lq * 4 + r) * 4 + wave] = mr[i * 4 + r];
    }
    __syncthreads();
    float m2[8];
#pragma unroll
    for (int i = 0; i < 2; i++)
#pragma unroll
        for (int r = 0; r < 4; r++) {
            float4 v = *(const float4*)&smax_s[(i * 16 + lq * 4 + r) * 4];
            m2[i * 4 + r] = fmaxf(fmaxf(v.x, v.y), fmaxf(v.z, v.w));
        }
    float sm[8];
#pragma unroll
    for (int k = 0; k < 8; k++) sm[k] = 0.f;
#pragma unroll
    for (int i = 0; i < 2; i++)
#pragma unroll
        for (int j = 0; j < 8; j++)
#pragma unroll
            for (int r = 0; r < 4; r++) {
                int row = i * 16 + lq * 4 + r;          // block-local [0,32)
                int col = wave * 128 + j * 16 + ln15;   // group-local [0,512)
                float e = (mt * 32 + row == col) ? 0.f
                          : __expf(accS[i][j][r] - m2[i * 4 + r]);
                sm[i * 4 + r] += e;
                Pl[row * 512 + (((col >> 3) ^ (row & 7)) << 3) + (col & 7)] = f2b(e);
            }
#pragma unroll
    for (int d = 1; d < 16; d <<= 1)
#pragma unroll
        for (int k = 0; k < 8; k++)
            sm[k] += __shfl_xor(sm[k], d);
    if (ln15 == 0) {
#pragma unroll
        for (int i = 0; i < 2; i++)
#pragma unroll
            for (int r = 0; r < 4; r++)
                ssum_s[(i * 16 + lq * 4 + r) * 4 + wave] = sm[i * 4 + r];
    }
    __syncthreads();
    if (wave == 0 && ln15 == 0) {    // one writer per row -> rinv[32]
#pragma unroll
        for (int i = 0; i < 2; i++)
#pragma unroll
            for (int r = 0; r < 4; r++) {
                int row = i * 16 + lq * 4 + r;
                float4 v = *(const float4*)&ssum_s[row * 4];
                rinv[row] = 1.0f / (v.x + v.y + v.z + v.w);
            }
    }
    __syncthreads();   // P + rinv visible; PV below is barrier-free

    // ---------------- Phase 3: O^T = V^T P^T (no barriers) ------------------
    // A-frag: m = dim (wave*192 + jj*16 + ln15), k = group-row (kt*32 + lq*8)
    const u16* Vg = vT + (long)(wave * 192 + ln15) * 8192 + grow0 + lq * 8;

    f32x4 accO[2][12];
#pragma unroll
    for (int i = 0; i < 2; i++)
#pragma unroll
        for (int j = 0; j < 12; j++)
            accO[i][j] = (f32x4){0.f, 0.f, 0.f, 0.f};

    bf16x8 va[2][12];
#pragma unroll
    for (int jj = 0; jj < 12; jj++)
        va[0][jj] = *(const bf16x8*)(Vg + (long)jj * 131072);

    for (int kt = 0; kt < 16; kt++) {
        const int cur = kt & 1, nxt = cur ^ 1;
        if (kt < 15) {
            const int o = (kt + 1) * 32;
#pragma unroll
            for (int jj = 0; jj < 12; jj++)
                va[nxt][jj] = *(const bf16x8*)(Vg + (long)jj * 131072 + o);
        }
        // B-frags: P[qrow = ln15 / 16+ln15][k = kt*32 + lq*8], swizzled
        const int cu = ((kt * 4 + lq) ^ (ln15 & 7)) << 3;
        bf16x8 p0 = *(const bf16x8*)(Pl + ln15 * 512 + cu);
        bf16x8 p1 = *(const bf16x8*)(Pl + (16 + ln15) * 512 + cu);
#pragma unroll
        for (int jj = 0; jj < 12; jj++) {
            accO[0][jj] = __builtin_amdgcn_mfma_f32_16x16x32_bf16(va[cur][jj], p0, accO[0][jj], 0, 0, 0);
            accO[1][jj] = __builtin_amdgcn_mfma_f32_16x16x32_bf16(va[cur][jj], p1, accO[1][jj], 0, 0, 0);
        }
    }

    // epilogue: O^T C-layout: m = wave*192 + jj*16 + lq*4 + r (dim),
    // n = qrow = ln15 (accO[0]) / 16+ln15 (accO[1]); normalize, bf16 store
    const float r0 = rinv[ln15], r1 = rinv[16 + ln15];
    u16* D0 = dyn + (grow0 + mt * 32 + ln15) * 768 + wave * 192 + lq * 4;
    u16* D1 = dyn + (grow0 + mt * 32 + 16 + ln15) * 768 + wave * 192 + lq * 4;
#pragma unroll
    for (int jj = 0; jj < 12; jj++) {
        ushort4 o0, o1;
        o0.x = f2b(accO[0][jj][0] * r0); o0.y = f2b(accO[0][jj][1] * r0);
        o0.z = f2b(accO[0][jj][2] * r0); o0.w = f2b(accO[0][jj][3] * r0);
        o1.x = f2b(accO[1][jj][0] * r1); o1.y = f2b(accO[1][jj][1] * r1);
        o1.z = f2b(accO[1][jj][2] * r1); o1.w = f2b(accO[1][jj][3] * r1);
        *(ushort4*)(D0 + jj * 16) = o0;
        *(ushort4*)(D1 + jj * 16) = o1;
    }
}

// ---------------------------------------------------------------------------
// launch
// ---------------------------------------------------------------------------
extern "C" void kernel_launch(void* const* d_in, const int* in_sizes, int n_in,
                              void* d_out, int out_size, void* d_ws, size_t ws_size,
                              hipStream_t stream)
{
    const float* x    = (const float*)d_in[0];
    // d_in[1] = batch (contiguous groups of 512; structure hardcoded)
    const float* Wq   = (const float*)d_in[2];
    const float* bq   = (const float*)d_in[3];
    const float* Wk   = (const float*)d_in[4];
    const float* bk   = (const float*)d_in[5];
    const float* Wv   = (const float*)d_in[6];
    const float* bv   = (const float*)d_in[7];
    const float* Wo   = (const float*)d_in[8];
    const float* bo   = (const float*)d_in[9];
    const float* beta = (const float*)d_in[10];
    float* out = (float*)d_out;

    char* ws = (char*)d_ws;
    // workspace (bytes), lifetime overlays; high-water 55,059,456 B
    u16*   qk    = (u16*)(ws + 0);            // [8192,1536] bf16  QKV->attn
    u16*   vT    = (u16*)(ws + 25165824);     // [768,8192]  bf16  QKV->attn
    u16*   xb    = (u16*)(ws + 37748736);     // [8192,768]  bf16  pack->QKV
    u16*   dyn   = (u16*)(ws + 37748736);     // [8192,768]  bf16  attn->out (aliases xb)
    u16*   Wqkvb = (u16*)(ws + 50331648);     // [2304,768]  bf16
    u16*   Wob   = (u16*)(ws + 53870592);     // [768,768]   bf16
    float* bqkv  = (float*)(ws + 55050240);   // [2304] f32

    const float scale = 0.03608439182435161f;  // 1/sqrt(768)

    pack_kernel<<<4224, 256, 0, stream>>>(x, Wq, Wk, Wv, Wo, bq, bk, bv,
                                          xb, Wqkvb, Wob, bqkv);

    // qkv = xb @ Wqkv^T + b : q|k -> qk [8192,1536]; v -> vT [768,8192] (T)
    gemm_bt<0><<<dim3(18, 64, 1), 256, 0, stream>>>(
        xb, 768, 0, Wqkvb, 768, 0, (void*)qk, 1536, 0, 768, bqkv, nullptr, nullptr, 0.f, vT);

    // fused scores+softmax+PV: dyn = softmax(scale*QK^T, blockdiag, no-self) V
    attn_fused<<<256, 256, 0, stream>>>(qk, vT, dyn, scale);

    // out = x + beta * (dyn @ Wo^T + bo)
    gemm_bt<4><<<dim3(6, 64, 1), 256, 0, stream>>>(
        dyn, 768, 0, Wob, 768, 0, (void*)out, 768, 0, 768, bo, x, beta, 0.f, nullptr);
}

// Round 6
// 216.459 us; speedup vs baseline: 1.1268x; 1.1268x over previous
//
#include <hip/hip_runtime.h>
#include <hip/hip_bf16.h>
#include <cstdint>

using u16 = unsigned short;
using u32 = unsigned int;

typedef __bf16 bf16x8 __attribute__((ext_vector_type(8)));
typedef float  f32x4  __attribute__((ext_vector_type(4)));

__device__ __forceinline__ u16 f2b(float f) {
    u32 u = __builtin_bit_cast(u32, f);
    u += 0x7fffu + ((u >> 16) & 1u);
    return (u16)(u >> 16);
}

// async global->LDS, 16B per lane; lds dst is wave-uniform base + lane*16
__device__ __forceinline__ void gload_lds16(const u16* g, u16* l) {
    __builtin_amdgcn_global_load_lds(
        (const __attribute__((address_space(1))) void*)g,
        (__attribute__((address_space(3))) void*)l,
        16, 0, 0);
}

// ---------------------------------------------------------------------------
// pack: fp32 -> bf16 casts (x, Wq|Wk|Wv concat, Wo) + bias concat bq|bk|bv
// ---------------------------------------------------------------------------
__launch_bounds__(256)
__global__ void pack_kernel(const float* __restrict__ x,
                            const float* __restrict__ Wq,
                            const float* __restrict__ Wk,
                            const float* __restrict__ Wv,
                            const float* __restrict__ Wo,
                            const float* __restrict__ bq,
                            const float* __restrict__ bk,
                            const float* __restrict__ bv,
                            u16* __restrict__ xb,
                            u16* __restrict__ Wqkvb,
                            u16* __restrict__ Wob,
                            float* __restrict__ bqkv)
{
    int c = blockIdx.x * 256 + threadIdx.x;   // 0 .. 1081343
    long e = (long)c * 8;
    const float* src; u16* dst; long off;
    if (e < 6291456L)      { src = x;  dst = xb;              off = e; }
    else if (e < 6881280L) { src = Wq; dst = Wqkvb;           off = e - 6291456L; }
    else if (e < 7471104L) { src = Wk; dst = Wqkvb + 589824;  off = e - 6881280L; }
    else if (e < 8060928L) { src = Wv; dst = Wqkvb + 1179648; off = e - 7471104L; }
    else                   { src = Wo; dst = Wob;             off = e - 8060928L; }
    float4 v0 = *(const float4*)(src + off);
    float4 v1 = *(const float4*)(src + off + 4);
    union { u16 u[8]; uint4 q; } o;
    o.u[0] = f2b(v0.x); o.u[1] = f2b(v0.y); o.u[2] = f2b(v0.z); o.u[3] = f2b(v0.w);
    o.u[4] = f2b(v1.x); o.u[5] = f2b(v1.y); o.u[6] = f2b(v1.z); o.u[7] = f2b(v1.w);
    *(uint4*)(dst + off) = o.q;
    if (c < 768)        bqkv[c] = bq[c];
    else if (c < 1536)  bqkv[c] = bk[c - 768];
    else if (c < 2304)  bqkv[c] = bv[c - 1536];
}

// ---------------------------------------------------------------------------
// gemm_bt<TM,TN,MODE>: C[m,n] = sum_k A[m,k]*B[n,k] (bf16, K-contiguous).
// TMxTN tile, 256 threads (2x2 waves, wave tile TM/2 x TN/2), dbuf LDS,
// global_load_lds width-16 staging, 1 barrier per K-step.
// MODE 0: QKV epilogue (cols<1536: bf16+bias -> C; cols>=1536: transposed
//         ushort4 (+bias) -> vTout [768,8192])
// MODE 2: f32 out, *scale, group-local diag = -1e9 (scores)
// MODE 3: bf16 out, no bias (PV)
// MODE 4: f32 out, out = xres + beta*(acc + bias[col])
// M,N multiples of TM/TN; K multiple of 32. blockIdx = (ntile, mtile, group)
// ---------------------------------------------------------------------------
template<int TM, int TN, int MODE>
__launch_bounds__(256)
__global__ void gemm_bt(const u16* __restrict__ A, int lda, long sAz,
                        const u16* __restrict__ B, int ldb, long sBz,
                        void* __restrict__ Cv, int ldc, long sCz,
                        int K,
                        const float* __restrict__ bias,
                        const float* __restrict__ xres,
                        const float* __restrict__ betaPtr,
                        float scale,
                        u16* __restrict__ vTout)
{
    constexpr int FI = TM / 32;      // A-frags per wave
    constexpr int FJ = TN / 32;      // B-frags per wave
    constexpr int CA = TM / 64;      // A staging chunks (1KB) per wave
    constexpr int CB = TN / 64;      // B staging chunks per wave

    __shared__ u16 As[2][TM * 32];
    __shared__ u16 Bs[2][TN * 32];

    const int tid  = threadIdx.x;
    const int g    = blockIdx.z;
    const u16* Ab = A + (long)g * sAz + (long)blockIdx.y * TM * lda;
    const u16* Bb = B + (long)g * sBz + (long)blockIdx.x * TN * ldb;

    const int wave = tid >> 6, lane = tid & 63;
    const int wm = (wave >> 1) * (TM / 2), wn = (wave & 1) * (TN / 2);
    const int ln15 = lane & 15, lq = lane >> 4;

    f32x4 acc[FI][FJ];
#pragma unroll
    for (int i = 0; i < FI; i++)
#pragma unroll
        for (int j = 0; j < FJ; j++)
            acc[i][j] = (f32x4){0.f, 0.f, 0.f, 0.f};

    // staging geometry: chunk c covers rows [c*16, c*16+16); lane L ->
    // row c*16 + L/4, col (L%4)*8; LDS dst = chunkbase + L*16B (linear).
    const int srow = lane >> 2, sc = (lane & 3) * 8;
    const u16* Ag[CA]; const u16* Bg[CB];
    int Al[CA], Bl[CB];
#pragma unroll
    for (int t = 0; t < CA; t++) {
        int c = wave * CA + t;
        Ag[t] = Ab + (long)(c * 16 + srow) * lda + sc;
        Al[t] = c * 512;
    }
#pragma unroll
    for (int t = 0; t < CB; t++) {
        int c = wave * CB + t;
        Bg[t] = Bb + (long)(c * 16 + srow) * ldb + sc;
        Bl[t] = c * 512;
    }

    const int nk = K >> 5;

    // prologue: stage K-step 0 into buffer 0
#pragma unroll
    for (int t = 0; t < CA; t++) gload_lds16(Ag[t], &As[0][Al[t]]);
#pragma unroll
    for (int t = 0; t < CB; t++) gload_lds16(Bg[t], &Bs[0][Bl[t]]);

    for (int kt = 0; kt < nk; kt++) {
        const int cur = kt & 1;
        __syncthreads();          // drains loads into buf[cur] + prior ds_reads
        if (kt + 1 < nk) {
            const int k0 = (kt + 1) * 32, nxt = cur ^ 1;
#pragma unroll
            for (int t = 0; t < CA; t++) gload_lds16(Ag[t] + k0, &As[nxt][Al[t]]);
#pragma unroll
            for (int t = 0; t < CB; t++) gload_lds16(Bg[t] + k0, &Bs[nxt][Bl[t]]);
        }

        bf16x8 af[FI], bfr[FJ];
#pragma unroll
        for (int i = 0; i < FI; i++)
            af[i] = *(const bf16x8*)&As[cur][(wm + i * 16 + ln15) * 32 + lq * 8];
#pragma unroll
        for (int j = 0; j < FJ; j++)
            bfr[j] = *(const bf16x8*)&Bs[cur][(wn + j * 16 + ln15) * 32 + lq * 8];
#pragma unroll
        for (int i = 0; i < FI; i++)
#pragma unroll
            for (int j = 0; j < FJ; j++)
                acc[i][j] = __builtin_amdgcn_mfma_f32_16x16x32_bf16(af[i], bfr[j], acc[i][j], 0, 0, 0);
    }

    const int baseRow = blockIdx.y * TM + wm;
    const int baseCol = blockIdx.x * TN + wn;

    if constexpr (MODE == 0) {
        if (baseCol < 1536) {
            u16* C = (u16*)Cv;
#pragma unroll
            for (int i = 0; i < FI; i++)
#pragma unroll
                for (int j = 0; j < FJ; j++)
#pragma unroll
                    for (int r = 0; r < 4; r++) {
                        int row = baseRow + i * 16 + lq * 4 + r;
                        int col = baseCol + j * 16 + ln15;
                        C[(long)row * ldc + col] = f2b(acc[i][j][r] + bias[col]);
                    }
        } else {
#pragma unroll
            for (int i = 0; i < FI; i++)
#pragma unroll
                for (int j = 0; j < FJ; j++) {
                    int col = baseCol + j * 16 + ln15;
                    float bb = bias[col];
                    ushort4 o;
                    o.x = f2b(acc[i][j][0] + bb);
                    o.y = f2b(acc[i][j][1] + bb);
                    o.z = f2b(acc[i][j][2] + bb);
                    o.w = f2b(acc[i][j][3] + bb);
                    *(ushort4*)(vTout + (long)(col - 1536) * 8192
                                + baseRow + i * 16 + lq * 4) = o;
                }
        }
    } else if constexpr (MODE == 2) {
        float* C = (float*)Cv + (long)g * sCz;
#pragma unroll
        for (int i = 0; i < FI; i++)
#pragma unroll
            for (int j = 0; j < FJ; j++)
#pragma unroll
                for (int r = 0; r < 4; r++) {
                    int row = baseRow + i * 16 + lq * 4 + r;
                    int col = baseCol + j * 16 + ln15;
                    float v = acc[i][j][r] * scale;
                    if (row == col) v = -1.0e9f;
                    C[(long)row * ldc + col] = v;
                }
    } else if constexpr (MODE == 3) {
        u16* C = (u16*)Cv + (long)g * sCz;
#pragma unroll
        for (int i = 0; i < FI; i++)
#pragma unroll
            for (int j = 0; j < FJ; j++)
#pragma unroll
                for (int r = 0; r < 4; r++) {
                    int row = baseRow + i * 16 + lq * 4 + r;
                    int col = baseCol + j * 16 + ln15;
                    C[(long)row * ldc + col] = f2b(acc[i][j][r]);
                }
    } else { // MODE 4
        float* C = (float*)Cv;
        float bet = betaPtr[0];
#pragma unroll
        for (int i = 0; i < FI; i++)
#pragma unroll
            for (int j = 0; j < FJ; j++)
#pragma unroll
                for (int r = 0; r < 4; r++) {
                    int row = baseRow + i * 16 + lq * 4 + r;
                    int col = baseCol + j * 16 + ln15;
                    float v = xres[(long)row * ldc + col] + bet * (acc[i][j][r] + bias[col]);
                    C[(long)row * ldc + col] = v;
                }
    }
}

// ---------------------------------------------------------------------------
// row softmax over 512 entries, one wave per row; S fp32 -> P bf16
// ---------------------------------------------------------------------------
__launch_bounds__(256)
__global__ void softmax_rows(const float* __restrict__ S, u16* __restrict__ P)
{
    int row  = blockIdx.x * 4 + (threadIdx.x >> 6);
    int lane = threadIdx.x & 63;
    const float* s = S + (long)row * 512 + lane * 8;
    float4 v0 = *(const float4*)s;
    float4 v1 = *(const float4*)(s + 4);
    float vv[8] = {v0.x, v0.y, v0.z, v0.w, v1.x, v1.y, v1.z, v1.w};
    float m = vv[0];
#pragma unroll
    for (int i = 1; i < 8; i++) m = fmaxf(m, vv[i]);
#pragma unroll
    for (int off = 32; off; off >>= 1) m = fmaxf(m, __shfl_xor(m, off));
    float e[8], sum = 0.f;
#pragma unroll
    for (int i = 0; i < 8; i++) { e[i] = __expf(vv[i] - m); sum += e[i]; }
#pragma unroll
    for (int off = 32; off; off >>= 1) sum += __shfl_xor(sum, off);
    float inv = 1.0f / sum;
    union { u16 u[8]; uint4 q; } o;
#pragma unroll
    for (int i = 0; i < 8; i++) o.u[i] = f2b(e[i] * inv);
    *(uint4*)(P + (long)row * 512 + lane * 8) = o.q;
}

// ---------------------------------------------------------------------------
// launch
// ---------------------------------------------------------------------------
extern "C" void kernel_launch(void* const* d_in, const int* in_sizes, int n_in,
                              void* d_out, int out_size, void* d_ws, size_t ws_size,
                              hipStream_t stream)
{
    const float* x    = (const float*)d_in[0];
    // d_in[1] = batch (contiguous groups of 512; structure hardcoded)
    const float* Wq   = (const float*)d_in[2];
    const float* bq   = (const float*)d_in[3];
    const float* Wk   = (const float*)d_in[4];
    const float* bk   = (const float*)d_in[5];
    const float* Wv   = (const float*)d_in[6];
    const float* bv   = (const float*)d_in[7];
    const float* Wo   = (const float*)d_in[8];
    const float* bo   = (const float*)d_in[9];
    const float* beta = (const float*)d_in[10];
    float* out = (float*)d_out;

    char* ws = (char*)d_ws;
    // workspace layout (bytes), lifetime overlays; high-water 64,103,424 B
    // lifetimes: xb/Wqkvb/bqkv: pack->QKV. qk: QKV->scores. vT: QKV->PV.
    //            S: scores->softmax. P: softmax->PV. dyn: PV->out. Wob: ->out.
    u16*   qk    = (u16*)(ws + 0);            // [8192,1536] bf16
    u16*   dyn   = (u16*)(ws + 0);            // [8192,768]  bf16 (aliases qk)
    u16*   vT    = (u16*)(ws + 25165824);     // [768,8192]  bf16
    u16*   xb    = (u16*)(ws + 37748736);     // [8192,768]  bf16
    float* S     = (float*)(ws + 37748736);   // [8192,512]  f32 (aliases xb+Wqkvb)
    u16*   Wqkvb = (u16*)(ws + 50331648);     // [2304,768]  bf16 (inside S tail; disjoint lifetime)
    u16*   Wob   = (u16*)(ws + 54525952);     // [768,768]   bf16
    float* bqkv  = (float*)(ws + 55705600);   // [2304] f32
    u16*   P     = (u16*)(ws + 55714816);     // [8192,512]  bf16 -> end 64,103,424

    const float scale = 0.03608439182435161f;  // 1/sqrt(768)

    pack_kernel<<<4224, 256, 0, stream>>>(x, Wq, Wk, Wv, Wo, bq, bk, bv,
                                          xb, Wqkvb, Wob, bqkv);

    // qkv = xb @ Wqkv^T + b : q|k -> qk [8192,1536]; v -> vT [768,8192] (T)
    gemm_bt<128, 128, 0><<<dim3(18, 64, 1), 256, 0, stream>>>(
        xb, 768, 0, Wqkvb, 768, 0, (void*)qk, 1536, 0, 768,
        bqkv, nullptr, nullptr, 0.f, vT);

    // per-group scores: S = scale * q_g k_g^T, group-local diag = -1e9
    gemm_bt<64, 128, 2><<<dim3(4, 8, 16), 256, 0, stream>>>(
        qk, 1536, 512L * 1536, qk + 768, 1536, 512L * 1536,
        (void*)S, 512, 512L * 512, 768, nullptr, nullptr, nullptr, scale, nullptr);

    softmax_rows<<<2048, 256, 0, stream>>>(S, P);

    // dyn_g = P_g @ v_g : A=P [512,512], B=vT (K-contig along group cols)
    gemm_bt<64, 128, 3><<<dim3(6, 8, 16), 256, 0, stream>>>(
        P, 512, 512L * 512, vT, 8192, 512L,
        (void*)dyn, 768, 512L * 768, 512, nullptr, nullptr, nullptr, 0.f, nullptr);

    // out = x + beta * (dyn @ Wo^T + bo)
    gemm_bt<64, 128, 4><<<dim3(6, 128, 1), 256, 0, stream>>>(
        dyn, 768, 0, Wob, 768, 0, (void*)out, 768, 0, 768,
        bo, x, beta, 0.f, nullptr);
}